// Round 4
// baseline (617.819 us; speedup 1.0000x reference)
//
#include <hip/hip_runtime.h>
#include <math.h>

#define NB 2
#define NS 2048
#define ND 768
#define NH 12
#define DH 64

#define BM 128
#define BN 128
#define BK 64

typedef __attribute__((ext_vector_type(8))) short short8;
typedef __attribute__((ext_vector_type(8))) __bf16 bf16x8;
typedef __attribute__((ext_vector_type(4))) float f32x4;

static __device__ inline unsigned short f2bf(float f) {
    unsigned int u = __float_as_uint(f);
    unsigned int r = (u + 0x7FFFu + ((u >> 16) & 1u)) >> 16;
    return (unsigned short)r;
}

static __device__ inline bf16x8 ld_bf8(const unsigned short* p) {
    short8 s = *(const short8*)p;
    return __builtin_bit_cast(bf16x8, s);
}

// async global->LDS, 16B per lane; LDS dest is wave-uniform base + lane*16
static __device__ inline void gload_lds16(const void* g, void* l) {
    __builtin_amdgcn_global_load_lds(
        (const __attribute__((address_space(1))) void*)g,
        (__attribute__((address_space(3))) void*)l, 16, 0, 0);
}

// ---------------------------------------------------------------------------
// Kernel 0: fp32 -> bf16 conversion (unchanged, verified).
// ---------------------------------------------------------------------------
struct CvtArgs {
    const float* src[7];
    unsigned short* dst[7];
    int n8[7];
};

__global__ __launch_bounds__(256) void cvt_kernel(CvtArgs a) {
    const int t = blockIdx.y;
    const float* __restrict__ s = a.src[t];
    unsigned short* __restrict__ d = a.dst[t];
    const int n8 = a.n8[t];
    for (int i = blockIdx.x * 256 + threadIdx.x; i < n8; i += gridDim.x * 256) {
        float4 f0 = ((const float4*)s)[(size_t)i * 2];
        float4 f1 = ((const float4*)s)[(size_t)i * 2 + 1];
        unsigned short pk[8] = { f2bf(f0.x), f2bf(f0.y), f2bf(f0.z), f2bf(f0.w),
                                 f2bf(f1.x), f2bf(f1.y), f2bf(f1.z), f2bf(f1.w) };
        *(short8*)(d + (size_t)i * 8) = *(short8*)pk;
    }
}

// ---------------------------------------------------------------------------
// Kernel 1: bf16 MFMA GEMM (unchanged, verified).
// ---------------------------------------------------------------------------
template<int MODE>
__global__ __launch_bounds__(256) void gemm_kernel(
    const unsigned short* __restrict__ A0, const unsigned short* __restrict__ A1,
    const unsigned short* __restrict__ A2,
    const unsigned short* __restrict__ B0, const unsigned short* __restrict__ B1,
    const unsigned short* __restrict__ B2,
    const float* __restrict__ bias0, const float* __restrict__ bias1,
    const float* __restrict__ bias2,
    void* __restrict__ out0, void* __restrict__ out1, void* __restrict__ out2)
{
    const int p = blockIdx.z;
    const unsigned short* A = (p == 0) ? A0 : (p == 1) ? A1 : A2;
    const unsigned short* B = (p == 0) ? B0 : (p == 1) ? B1 : B2;
    const float* bias = (p == 0) ? bias0 : (p == 1) ? bias1 : bias2;
    void* outp = (p == 0) ? out0 : (p == 1) ? out1 : out2;
    const float qscale = (MODE == 0 && p == 0) ? 0.125f : 1.0f;

    const int m0 = blockIdx.y * BM;
    const int n0 = blockIdx.x * BN;
    const int tid = threadIdx.x;
    const int wave = tid >> 6, lane = tid & 63;
    const int wr = wave >> 1, wc = wave & 1;
    const int c = lane & 15, quad = lane >> 4;

    __shared__ __align__(16) unsigned short As[BM * BK];
    __shared__ __align__(16) unsigned short Bs[BN * BK];

    f32x4 acc[4][4] = {};

    const int srow0 = wave * 8 + (lane >> 3);
    const int slane8 = lane & 7;

    for (int k0 = 0; k0 < ND; k0 += BK) {
#pragma unroll
        for (int j = 0; j < 4; ++j) {
            const int row = j * 32 + srow0;
            const int chunk = slane8 ^ (row & 7);
            gload_lds16(A + (size_t)(m0 + row) * ND + k0 + chunk * 8,
                        &As[j * 2048 + wave * 512]);
            gload_lds16(B + (size_t)(n0 + row) * ND + k0 + chunk * 8,
                        &Bs[j * 2048 + wave * 512]);
        }
        __syncthreads();

#pragma unroll
        for (int ks = 0; ks < 2; ++ks) {
            bf16x8 af[4], bfv[4];
#pragma unroll
            for (int i = 0; i < 4; ++i) {
                const int rA = wr * 64 + i * 16 + c;
                af[i] = ld_bf8(&As[rA * 64 + ((ks * 32 + quad * 8) ^ ((rA & 7) << 3))]);
                const int rB = wc * 64 + i * 16 + c;
                bfv[i] = ld_bf8(&Bs[rB * 64 + ((ks * 32 + quad * 8) ^ ((rB & 7) << 3))]);
            }
#pragma unroll
            for (int i = 0; i < 4; ++i)
#pragma unroll
                for (int j = 0; j < 4; ++j)
                    acc[i][j] = __builtin_amdgcn_mfma_f32_16x16x32_bf16(
                        af[i], bfv[j], acc[i][j], 0, 0, 0);
        }
        __syncthreads();
    }

    float bj[4];
#pragma unroll
    for (int j = 0; j < 4; ++j) bj[j] = bias[n0 + wc * 64 + j * 16 + c];

    if (MODE == 0) {
        unsigned short* out = (unsigned short*)outp;
        const int h = (n0 >> 6) + wc;
#pragma unroll
        for (int i = 0; i < 4; ++i) {
#pragma unroll
            for (int r = 0; r < 4; ++r) {
                const int m = m0 + wr * 64 + i * 16 + quad * 4 + r;
                const int bb = m >> 11, s = m & (NS - 1);
                unsigned short* orow = out + (((size_t)bb * NH + h) * NS + s) * DH;
#pragma unroll
                for (int j = 0; j < 4; ++j)
                    orow[j * 16 + c] = f2bf((acc[i][j][r] + bj[j]) * qscale);
            }
        }
    } else {
        float* out = (float*)outp;
#pragma unroll
        for (int i = 0; i < 4; ++i) {
#pragma unroll
            for (int r = 0; r < 4; ++r) {
                const int m = m0 + wr * 64 + i * 16 + quad * 4 + r;
                float* orow = out + (size_t)m * ND + n0 + wc * 64;
#pragma unroll
                for (int j = 0; j < 4; ++j)
                    orow[j * 16 + c] = acc[i][j][r] + bj[j];
            }
        }
    }
}

// ---------------------------------------------------------------------------
// Kernel 2: MFMA attention with 2-phase pipeline (T3-minimum recipe).
//  - Pass A: double-buffered Ka; next tile's global_load_lds issued BEFORE
//    computing current tile; ONE barrier per tile (was 2). No max-tracking
//    (scores O(+-7); masked -> exp underflows to exact 0).
//  - Pass B: double-buffered Ks (gload_lds) + Vt; V global loads issued at
//    loop top (T14 issue-early), transpose-write to buf^1 after compute;
//    ONE barrier per tile. s_setprio(1) around the PV MFMA cluster.
// LDS: union(Ka 32KB | Ks 16KB + Vt 18KB + Ps 9KB) + madd 8KB = 52KB,
// 3 blocks/CU (was 4; pipeline > occupancy per T3 evidence).
// ---------------------------------------------------------------------------
__global__ __launch_bounds__(256) void attn_kernel(
    const unsigned short* __restrict__ qg, const unsigned short* __restrict__ kg,
    const unsigned short* __restrict__ vg, const int* __restrict__ mask,
    float* __restrict__ probs, unsigned short* __restrict__ attnout)
{
    const int bh = blockIdx.y;
    const int b = bh / NH, h = bh % NH;
    const int q0 = blockIdx.x * 64;
    const int tid  = threadIdx.x;
    const int w    = tid >> 6;
    const int lane = tid & 63;
    const int quad = lane >> 4;
    const int c    = lane & 15;

    __shared__ union {
        unsigned short Ka[2][128 * 64];              // pass A dbuf, linear+swz
        struct {
            unsigned short Ks[2][64 * 64];           // pass B K dbuf, linear+swz
            unsigned short Vt[2][64][72];            // V transposed dbuf [d][s]
            unsigned short Ps[4][16][72];            // per-wave P bf16 [q][k]
        } b;
    } sm;
    __shared__ float madd[NS];

    const int* mrow = mask + b * NS;
    for (int i = tid; i < NS; i += 256) madd[i] = mrow[i] ? 0.0f : -1.0e9f;

    const size_t hb = (size_t)bh * NS;

    // Q fragments (pre-scaled by 0.125), held for both passes
    const unsigned short* qrow = qg + (hb + q0 + w * 16 + c) * DH;
    bf16x8 afrag0 = ld_bf8(qrow + quad * 8);
    bf16x8 afrag1 = ld_bf8(qrow + 32 + quad * 8);

    // staging geometry (gload_lds): row = j*32 + wave*8 + (lane>>3),
    // source chunk = (lane&7) ^ (row&7); row&7 == lane>>3
    const int srow0 = w * 8 + (lane >> 3);
    const int schunk = (lane & 7) ^ (lane >> 3);
    // read-side swizzle: row = nt*16 + c -> row&7 = c&7
    const int rsw = (quad ^ (c & 7)) << 3;           // b0 pos; b1 = rsw ^ 32

    // ---------------- pass A: row sums, 2-phase pipelined ----------------
    float l_r[4] = {0.f, 0.f, 0.f, 0.f};

    // prologue: stage tile 0 into Ka[0]
#pragma unroll
    for (int j = 0; j < 4; ++j) {
        const int row = j * 32 + srow0;
        gload_lds16(kg + (hb + row) * DH + schunk * 8,
                    &sm.Ka[0][(j * 32 + w * 8) * 64]);
    }
    __syncthreads();

    int cur = 0;
    for (int kt = 0; kt < NS / 128; ++kt) {
        const int k0 = kt * 128;
        if (kt + 1 < NS / 128) {                     // issue next tile's loads
            const int k0n = k0 + 128;
#pragma unroll
            for (int j = 0; j < 4; ++j) {
                const int row = j * 32 + srow0;
                gload_lds16(kg + (hb + k0n + row) * DH + schunk * 8,
                            &sm.Ka[cur ^ 1][(j * 32 + w * 8) * 64]);
            }
        }
        const unsigned short* Kc = &sm.Ka[cur][0];
#pragma unroll
        for (int nt = 0; nt < 8; ++nt) {
            const int row = nt * 16 + c;
            bf16x8 b0 = ld_bf8(&Kc[row * 64 + rsw]);
            bf16x8 b1 = ld_bf8(&Kc[row * 64 + (rsw ^ 32)]);
            f32x4 C = {0.f, 0.f, 0.f, 0.f};
            C = __builtin_amdgcn_mfma_f32_16x16x32_bf16(afrag0, b0, C, 0, 0, 0);
            C = __builtin_amdgcn_mfma_f32_16x16x32_bf16(afrag1, b1, C, 0, 0, 0);
            const float ma = madd[k0 + nt * 16 + c];
#pragma unroll
            for (int r = 0; r < 4; ++r) l_r[r] += __expf(C[r] + ma);
        }
        __syncthreads();                             // drains next-tile loads too
        cur ^= 1;
    }

    float linv[4];
#pragma unroll
    for (int r = 0; r < 4; ++r) {
        float s = l_r[r];
        s += __shfl_xor(s, 1);
        s += __shfl_xor(s, 2);
        s += __shfl_xor(s, 4);
        s += __shfl_xor(s, 8);
        linv[r] = 1.0f / s;
    }

    // ---------------- pass B: 2-phase pipelined ----------------
    f32x4 o[4] = {{0.f,0.f,0.f,0.f},{0.f,0.f,0.f,0.f},{0.f,0.f,0.f,0.f},{0.f,0.f,0.f,0.f}};
    const size_t prow = ((size_t)bh * NS + q0 + w * 16) * NS;
    const int d0 = w * 16;

    // prologue: stage K tile 0, load+write V tile 0
    short8 vx0, vx1;
#pragma unroll
    for (int j = 0; j < 2; ++j) {
        const int row = j * 32 + srow0;
        gload_lds16(kg + (hb + row) * DH + schunk * 8,
                    &sm.b.Ks[0][(j * 32 + w * 8) * 64]);
    }
    {
        const unsigned short* vsrc = vg + (hb + lane) * DH + d0;
        vx0 = *(const short8*)vsrc;
        vx1 = *(const short8*)(vsrc + 8);
    }
#pragma unroll
    for (int j = 0; j < 8; ++j) {
        sm.b.Vt[0][d0 + j][lane]     = (unsigned short)vx0[j];
        sm.b.Vt[0][d0 + 8 + j][lane] = (unsigned short)vx1[j];
    }
    __syncthreads();

    cur = 0;
    for (int kt = 0; kt < NS / 64; ++kt) {
        const int k0 = kt * 64;
        const bool more = (kt + 1 < NS / 64);
        if (more) {                                  // issue next K gloads + V reg loads
            const int k0n = k0 + 64;
#pragma unroll
            for (int j = 0; j < 2; ++j) {
                const int row = j * 32 + srow0;
                gload_lds16(kg + (hb + k0n + row) * DH + schunk * 8,
                            &sm.b.Ks[cur ^ 1][(j * 32 + w * 8) * 64]);
            }
            const unsigned short* vsrc = vg + (hb + k0n + lane) * DH + d0;
            vx0 = *(const short8*)vsrc;
            vx1 = *(const short8*)(vsrc + 8);
        }

        const unsigned short* Kc = &sm.b.Ks[cur][0];
#pragma unroll
        for (int nt = 0; nt < 4; ++nt) {
            const int row = nt * 16 + c;
            bf16x8 b0 = ld_bf8(&Kc[row * 64 + rsw]);
            bf16x8 b1 = ld_bf8(&Kc[row * 64 + (rsw ^ 32)]);
            f32x4 C = {0.f, 0.f, 0.f, 0.f};
            C = __builtin_amdgcn_mfma_f32_16x16x32_bf16(afrag0, b0, C, 0, 0, 0);
            C = __builtin_amdgcn_mfma_f32_16x16x32_bf16(afrag1, b1, C, 0, 0, 0);
            const float ma = madd[k0 + nt * 16 + c];
#pragma unroll
            for (int r = 0; r < 4; ++r) {
                float pv = __expf(C[r] + ma) * linv[r];
                probs[prow + (size_t)(quad * 4 + r) * NS + k0 + nt * 16 + c] = pv;
                sm.b.Ps[w][quad * 4 + r][nt * 16 + c] = f2bf(pv);
            }
        }

        // PV: A = P (wave-private), B = Vt[cur]
        bf16x8 pa0 = ld_bf8(&sm.b.Ps[w][c][quad * 8]);
        bf16x8 pa1 = ld_bf8(&sm.b.Ps[w][c][32 + quad * 8]);
        __builtin_amdgcn_s_setprio(1);
#pragma unroll
        for (int dt = 0; dt < 4; ++dt) {
            bf16x8 vb0 = ld_bf8(&sm.b.Vt[cur][dt * 16 + c][quad * 8]);
            bf16x8 vb1 = ld_bf8(&sm.b.Vt[cur][dt * 16 + c][32 + quad * 8]);
            o[dt] = __builtin_amdgcn_mfma_f32_16x16x32_bf16(pa0, vb0, o[dt], 0, 0, 0);
            o[dt] = __builtin_amdgcn_mfma_f32_16x16x32_bf16(pa1, vb1, o[dt], 0, 0, 0);
        }
        __builtin_amdgcn_s_setprio(0);

        if (more) {                                  // write next V tile (other buffer)
#pragma unroll
            for (int j = 0; j < 8; ++j) {
                sm.b.Vt[cur ^ 1][d0 + j][lane]     = (unsigned short)vx0[j];
                sm.b.Vt[cur ^ 1][d0 + 8 + j][lane] = (unsigned short)vx1[j];
            }
        }
        __syncthreads();
        cur ^= 1;
    }

    // epilogue: attn out bf16 [B,S,D]
#pragma unroll
    for (int dt = 0; dt < 4; ++dt) {
#pragma unroll
        for (int r = 0; r < 4; ++r) {
            int s = q0 + w * 16 + quad * 4 + r;
            attnout[((size_t)b * NS + s) * ND + h * DH + dt * 16 + c] = f2bf(o[dt][r]);
        }
    }
}

// ---------------------------------------------------------------------------
extern "C" void kernel_launch(void* const* d_in, const int* in_sizes, int n_in,
                              void* d_out, int out_size, void* d_ws, size_t ws_size,
                              hipStream_t stream) {
    const float* query = (const float*)d_in[0];
    const float* key   = (const float*)d_in[1];
    const float* value = (const float*)d_in[2];
    const int*   amask = (const int*)d_in[3];
    const float* wq = (const float*)d_in[4];
    const float* bq = (const float*)d_in[5];
    const float* wk = (const float*)d_in[6];
    const float* bk = (const float*)d_in[7];
    const float* wv = (const float*)d_in[8];
    const float* bv = (const float*)d_in[9];
    const float* wo = (const float*)d_in[10];
    const float* bo = (const float*)d_in[11];

    const size_t elems  = (size_t)NB * NS * ND;   // 3,145,728
    const size_t welems = (size_t)ND * ND;        // 589,824

    float* out   = (float*)d_out;                 // [B,S,D]
    float* probs = out + elems;                   // [B,H,S,S]

    // bf16 x-copies as scratch inside probs (consumed before probs written)
    unsigned short* xq_bf = (unsigned short*)probs;
    unsigned short* xk_bf = xq_bf + elems;
    unsigned short* xv_bf = xk_bf + elems;

    unsigned short* qbf   = (unsigned short*)d_ws;
    unsigned short* kbf   = qbf + elems;
    unsigned short* vbf   = kbf + elems;
    unsigned short* abf   = vbf + elems;
    unsigned short* wq_bf = abf + elems;
    unsigned short* wk_bf = wq_bf + welems;
    unsigned short* wv_bf = wk_bf + welems;
    unsigned short* wo_bf = wv_bf + welems;

    CvtArgs ca;
    ca.src[0] = query; ca.dst[0] = xq_bf; ca.n8[0] = (int)(elems / 8);
    ca.src[1] = key;   ca.dst[1] = xk_bf; ca.n8[1] = (int)(elems / 8);
    ca.src[2] = value; ca.dst[2] = xv_bf; ca.n8[2] = (int)(elems / 8);
    ca.src[3] = wq;    ca.dst[3] = wq_bf; ca.n8[3] = (int)(welems / 8);
    ca.src[4] = wk;    ca.dst[4] = wk_bf; ca.n8[4] = (int)(welems / 8);
    ca.src[5] = wv;    ca.dst[5] = wv_bf; ca.n8[5] = (int)(welems / 8);
    ca.src[6] = wo;    ca.dst[6] = wo_bf; ca.n8[6] = (int)(welems / 8);
    cvt_kernel<<<dim3(512, 7, 1), 256, 0, stream>>>(ca);

    gemm_kernel<0><<<dim3(ND / BN, (NB * NS) / BM, 3), 256, 0, stream>>>(
        xq_bf, xk_bf, xv_bf, wq_bf, wk_bf, wv_bf, bq, bk, bv, qbf, kbf, vbf);

    attn_kernel<<<dim3(NS / 64, NB * NH), 256, 0, stream>>>(
        qbf, kbf, vbf, amask, probs, abf);

    gemm_kernel<1><<<dim3(ND / BN, (NB * NS) / BM, 1), 256, 0, stream>>>(
        abf, abf, abf, wo_bf, wo_bf, wo_bf, bo, bo, bo, out, out, out);
}

// Round 5
// 573.275 us; speedup vs baseline: 1.0777x; 1.0777x over previous
//
#include <hip/hip_runtime.h>
#include <math.h>

#define NB 2
#define NS 2048
#define ND 768
#define NH 12
#define DH 64

#define BM 128
#define BN 128
#define BK 64

typedef __attribute__((ext_vector_type(8))) short short8;
typedef __attribute__((ext_vector_type(8))) __bf16 bf16x8;
typedef __attribute__((ext_vector_type(4))) float f32x4;

static __device__ inline unsigned short f2bf(float f) {
    unsigned int u = __float_as_uint(f);
    unsigned int r = (u + 0x7FFFu + ((u >> 16) & 1u)) >> 16;
    return (unsigned short)r;
}

static __device__ inline bf16x8 ld_bf8(const unsigned short* p) {
    short8 s = *(const short8*)p;
    return __builtin_bit_cast(bf16x8, s);
}

// async global->LDS, 16B per lane; LDS dest is wave-uniform base + lane*16
static __device__ inline void gload_lds16(const void* g, void* l) {
    __builtin_amdgcn_global_load_lds(
        (const __attribute__((address_space(1))) void*)g,
        (__attribute__((address_space(3))) void*)l, 16, 0, 0);
}

// ---------------------------------------------------------------------------
// Kernel 0: fp32 -> bf16 conversion (unchanged, verified).
// ---------------------------------------------------------------------------
struct CvtArgs {
    const float* src[7];
    unsigned short* dst[7];
    int n8[7];
};

__global__ __launch_bounds__(256) void cvt_kernel(CvtArgs a) {
    const int t = blockIdx.y;
    const float* __restrict__ s = a.src[t];
    unsigned short* __restrict__ d = a.dst[t];
    const int n8 = a.n8[t];
    for (int i = blockIdx.x * 256 + threadIdx.x; i < n8; i += gridDim.x * 256) {
        float4 f0 = ((const float4*)s)[(size_t)i * 2];
        float4 f1 = ((const float4*)s)[(size_t)i * 2 + 1];
        unsigned short pk[8] = { f2bf(f0.x), f2bf(f0.y), f2bf(f0.z), f2bf(f0.w),
                                 f2bf(f1.x), f2bf(f1.y), f2bf(f1.z), f2bf(f1.w) };
        *(short8*)(d + (size_t)i * 8) = *(short8*)pk;
    }
}

// ---------------------------------------------------------------------------
// Kernel 1: bf16 MFMA GEMM (unchanged, verified).
// ---------------------------------------------------------------------------
template<int MODE>
__global__ __launch_bounds__(256) void gemm_kernel(
    const unsigned short* __restrict__ A0, const unsigned short* __restrict__ A1,
    const unsigned short* __restrict__ A2,
    const unsigned short* __restrict__ B0, const unsigned short* __restrict__ B1,
    const unsigned short* __restrict__ B2,
    const float* __restrict__ bias0, const float* __restrict__ bias1,
    const float* __restrict__ bias2,
    void* __restrict__ out0, void* __restrict__ out1, void* __restrict__ out2)
{
    const int p = blockIdx.z;
    const unsigned short* A = (p == 0) ? A0 : (p == 1) ? A1 : A2;
    const unsigned short* B = (p == 0) ? B0 : (p == 1) ? B1 : B2;
    const float* bias = (p == 0) ? bias0 : (p == 1) ? bias1 : bias2;
    void* outp = (p == 0) ? out0 : (p == 1) ? out1 : out2;
    const float qscale = (MODE == 0 && p == 0) ? 0.125f : 1.0f;

    const int m0 = blockIdx.y * BM;
    const int n0 = blockIdx.x * BN;
    const int tid = threadIdx.x;
    const int wave = tid >> 6, lane = tid & 63;
    const int wr = wave >> 1, wc = wave & 1;
    const int c = lane & 15, quad = lane >> 4;

    __shared__ __align__(16) unsigned short As[BM * BK];
    __shared__ __align__(16) unsigned short Bs[BN * BK];

    f32x4 acc[4][4] = {};

    const int srow0 = wave * 8 + (lane >> 3);
    const int slane8 = lane & 7;

    for (int k0 = 0; k0 < ND; k0 += BK) {
#pragma unroll
        for (int j = 0; j < 4; ++j) {
            const int row = j * 32 + srow0;
            const int chunk = slane8 ^ (row & 7);
            gload_lds16(A + (size_t)(m0 + row) * ND + k0 + chunk * 8,
                        &As[j * 2048 + wave * 512]);
            gload_lds16(B + (size_t)(n0 + row) * ND + k0 + chunk * 8,
                        &Bs[j * 2048 + wave * 512]);
        }
        __syncthreads();

#pragma unroll
        for (int ks = 0; ks < 2; ++ks) {
            bf16x8 af[4], bfv[4];
#pragma unroll
            for (int i = 0; i < 4; ++i) {
                const int rA = wr * 64 + i * 16 + c;
                af[i] = ld_bf8(&As[rA * 64 + ((ks * 32 + quad * 8) ^ ((rA & 7) << 3))]);
                const int rB = wc * 64 + i * 16 + c;
                bfv[i] = ld_bf8(&Bs[rB * 64 + ((ks * 32 + quad * 8) ^ ((rB & 7) << 3))]);
            }
#pragma unroll
            for (int i = 0; i < 4; ++i)
#pragma unroll
                for (int j = 0; j < 4; ++j)
                    acc[i][j] = __builtin_amdgcn_mfma_f32_16x16x32_bf16(
                        af[i], bfv[j], acc[i][j], 0, 0, 0);
        }
        __syncthreads();
    }

    float bj[4];
#pragma unroll
    for (int j = 0; j < 4; ++j) bj[j] = bias[n0 + wc * 64 + j * 16 + c];

    if (MODE == 0) {
        unsigned short* out = (unsigned short*)outp;
        const int h = (n0 >> 6) + wc;
#pragma unroll
        for (int i = 0; i < 4; ++i) {
#pragma unroll
            for (int r = 0; r < 4; ++r) {
                const int m = m0 + wr * 64 + i * 16 + quad * 4 + r;
                const int bb = m >> 11, s = m & (NS - 1);
                unsigned short* orow = out + (((size_t)bb * NH + h) * NS + s) * DH;
#pragma unroll
                for (int j = 0; j < 4; ++j)
                    orow[j * 16 + c] = f2bf((acc[i][j][r] + bj[j]) * qscale);
            }
        }
    } else {
        float* out = (float*)outp;
#pragma unroll
        for (int i = 0; i < 4; ++i) {
#pragma unroll
            for (int r = 0; r < 4; ++r) {
                const int m = m0 + wr * 64 + i * 16 + quad * 4 + r;
                float* orow = out + (size_t)m * ND + n0 + wc * 64;
#pragma unroll
                for (int j = 0; j < 4; ++j)
                    orow[j * 16 + c] = acc[i][j][r] + bj[j];
            }
        }
    }
}

// ---------------------------------------------------------------------------
// Kernel 2: MFMA attention (Round-3 verified structure) + XCD-aware block
// swizzle: all 32 q-tile blocks of a given (b,h) land on ONE XCD (3 bh per
// XCD), so K/V/Q staging is XCD-L2-resident (1.5 MB << 4 MB) instead of
// being re-fetched into all 8 per-XCD L2s.
// LDS: union(Ka 16KB | Ks 8KB + Vt 9KB + Ps 9KB) + madd 8KB = 34.8KB.
// ---------------------------------------------------------------------------
__global__ __launch_bounds__(256) void attn_kernel(
    const unsigned short* __restrict__ qg, const unsigned short* __restrict__ kg,
    const unsigned short* __restrict__ vg, const int* __restrict__ mask,
    float* __restrict__ probs, unsigned short* __restrict__ attnout)
{
    // XCD swizzle: physical linear id -> (bh, q-tile) such that each XCD
    // (lin & 7 under round-robin dispatch) owns 3 complete bh groups.
    const int lin = blockIdx.x + blockIdx.y * gridDim.x;   // 0..767
    const int xcd = lin & 7;
    const int jj  = lin >> 3;                              // 0..95
    const int bh  = xcd * 3 + (jj >> 5);                   // bijective: 24 bh
    const int q0  = (jj & 31) * 64;

    const int b = bh / NH, h = bh % NH;
    const int tid  = threadIdx.x;
    const int w    = tid >> 6;
    const int lane = tid & 63;
    const int quad = lane >> 4;
    const int c    = lane & 15;

    __shared__ union {
        unsigned short Ka[128 * 64];                 // pass A: 128 K-rows, linear+swz
        struct {
            unsigned short Ks[64 * 64];              // pass B: 64 K-rows, linear+swz
            unsigned short Vt[64][72];               // V transposed [d][s]
            unsigned short Ps[4][16][72];            // per-wave P bf16 [q][k]
        } b;
    } sm;
    __shared__ float madd[NS];

    const int* mrow = mask + b * NS;
    for (int i = tid; i < NS; i += 256) madd[i] = mrow[i] ? 0.0f : -1.0e9f;

    const size_t hb = (size_t)bh * NS;

    // Q fragments (pre-scaled by 0.125), held for both passes
    const unsigned short* qrow = qg + (hb + q0 + w * 16 + c) * DH;
    bf16x8 afrag0 = ld_bf8(qrow + quad * 8);
    bf16x8 afrag1 = ld_bf8(qrow + 32 + quad * 8);

    // staging geometry (gload_lds): row = j*32 + wave*8 + (lane>>3),
    // source chunk = (lane&7) ^ (row&7); row&7 == lane>>3
    const int srow0 = w * 8 + (lane >> 3);
    const int schunk = (lane & 7) ^ (lane >> 3);
    // read-side swizzle: row = nt*16 + c -> row&7 = c&7
    const int rsw = (quad ^ (c & 7)) << 3;           // b0 pos; b1 = rsw ^ 32

    // ---------------- pass A: row sums ----------------
    float l_r[4] = {0.f, 0.f, 0.f, 0.f};

    for (int kt = 0; kt < NS / 128; ++kt) {
        const int k0 = kt * 128;
#pragma unroll
        for (int j = 0; j < 4; ++j) {
            const int row = j * 32 + srow0;
            gload_lds16(kg + (hb + k0 + row) * DH + schunk * 8,
                        &sm.Ka[(j * 32 + w * 8) * 64]);
        }
        __syncthreads();

#pragma unroll
        for (int nt = 0; nt < 8; ++nt) {
            const int row = nt * 16 + c;
            bf16x8 b0 = ld_bf8(&sm.Ka[row * 64 + rsw]);
            bf16x8 b1 = ld_bf8(&sm.Ka[row * 64 + (rsw ^ 32)]);
            f32x4 C = {0.f, 0.f, 0.f, 0.f};
            C = __builtin_amdgcn_mfma_f32_16x16x32_bf16(afrag0, b0, C, 0, 0, 0);
            C = __builtin_amdgcn_mfma_f32_16x16x32_bf16(afrag1, b1, C, 0, 0, 0);
            const float ma = madd[k0 + nt * 16 + c];
#pragma unroll
            for (int r = 0; r < 4; ++r) l_r[r] += __expf(C[r] + ma);
        }
        __syncthreads();
    }

    float linv[4];
#pragma unroll
    for (int r = 0; r < 4; ++r) {
        float s = l_r[r];
        s += __shfl_xor(s, 1);
        s += __shfl_xor(s, 2);
        s += __shfl_xor(s, 4);
        s += __shfl_xor(s, 8);
        linv[r] = 1.0f / s;
    }

    // ---------------- pass B ----------------
    f32x4 o[4] = {{0.f,0.f,0.f,0.f},{0.f,0.f,0.f,0.f},{0.f,0.f,0.f,0.f},{0.f,0.f,0.f,0.f}};
    const size_t prow = ((size_t)bh * NS + q0 + w * 16) * NS;

    for (int kt = 0; kt < NS / 64; ++kt) {
        const int k0 = kt * 64;
#pragma unroll
        for (int j = 0; j < 2; ++j) {
            const int row = j * 32 + srow0;
            gload_lds16(kg + (hb + k0 + row) * DH + schunk * 8,
                        &sm.b.Ks[(j * 32 + w * 8) * 64]);
        }
        {
            // V transposed: wave w stages d-rows [w*16, w*16+16), s = lane
            const int d0 = w * 16;
            const unsigned short* vsrc = vg + (hb + k0 + lane) * DH + d0;
            short8 x0 = *(const short8*)vsrc;
            short8 x1 = *(const short8*)(vsrc + 8);
#pragma unroll
            for (int j = 0; j < 8; ++j) {
                sm.b.Vt[d0 + j][lane]     = (unsigned short)x0[j];
                sm.b.Vt[d0 + 8 + j][lane] = (unsigned short)x1[j];
            }
        }
        __syncthreads();

#pragma unroll
        for (int nt = 0; nt < 4; ++nt) {
            const int row = nt * 16 + c;
            bf16x8 b0 = ld_bf8(&sm.b.Ks[row * 64 + rsw]);
            bf16x8 b1 = ld_bf8(&sm.b.Ks[row * 64 + (rsw ^ 32)]);
            f32x4 C = {0.f, 0.f, 0.f, 0.f};
            C = __builtin_amdgcn_mfma_f32_16x16x32_bf16(afrag0, b0, C, 0, 0, 0);
            C = __builtin_amdgcn_mfma_f32_16x16x32_bf16(afrag1, b1, C, 0, 0, 0);
            const float ma = madd[k0 + nt * 16 + c];
#pragma unroll
            for (int r = 0; r < 4; ++r) {
                float pv = __expf(C[r] + ma) * linv[r];
                probs[prow + (size_t)(quad * 4 + r) * NS + k0 + nt * 16 + c] = pv;
                sm.b.Ps[w][quad * 4 + r][nt * 16 + c] = f2bf(pv);
            }
        }

        // PV: A = P (wave-private), B = Vt
        bf16x8 pa0 = ld_bf8(&sm.b.Ps[w][c][quad * 8]);
        bf16x8 pa1 = ld_bf8(&sm.b.Ps[w][c][32 + quad * 8]);
#pragma unroll
        for (int dt = 0; dt < 4; ++dt) {
            bf16x8 vb0 = ld_bf8(&sm.b.Vt[dt * 16 + c][quad * 8]);
            bf16x8 vb1 = ld_bf8(&sm.b.Vt[dt * 16 + c][32 + quad * 8]);
            o[dt] = __builtin_amdgcn_mfma_f32_16x16x32_bf16(pa0, vb0, o[dt], 0, 0, 0);
            o[dt] = __builtin_amdgcn_mfma_f32_16x16x32_bf16(pa1, vb1, o[dt], 0, 0, 0);
        }
        __syncthreads();
    }

    // epilogue: attn out bf16 [B,S,D]
#pragma unroll
    for (int dt = 0; dt < 4; ++dt) {
#pragma unroll
        for (int r = 0; r < 4; ++r) {
            int s = q0 + w * 16 + quad * 4 + r;
            attnout[((size_t)b * NS + s) * ND + h * DH + dt * 16 + c] = f2bf(o[dt][r]);
        }
    }
}

// ---------------------------------------------------------------------------
extern "C" void kernel_launch(void* const* d_in, const int* in_sizes, int n_in,
                              void* d_out, int out_size, void* d_ws, size_t ws_size,
                              hipStream_t stream) {
    const float* query = (const float*)d_in[0];
    const float* key   = (const float*)d_in[1];
    const float* value = (const float*)d_in[2];
    const int*   amask = (const int*)d_in[3];
    const float* wq = (const float*)d_in[4];
    const float* bq = (const float*)d_in[5];
    const float* wk = (const float*)d_in[6];
    const float* bk = (const float*)d_in[7];
    const float* wv = (const float*)d_in[8];
    const float* bv = (const float*)d_in[9];
    const float* wo = (const float*)d_in[10];
    const float* bo = (const float*)d_in[11];

    const size_t elems  = (size_t)NB * NS * ND;   // 3,145,728
    const size_t welems = (size_t)ND * ND;        // 589,824

    float* out   = (float*)d_out;                 // [B,S,D]
    float* probs = out + elems;                   // [B,H,S,S]

    // bf16 x-copies as scratch inside probs (consumed before probs written)
    unsigned short* xq_bf = (unsigned short*)probs;
    unsigned short* xk_bf = xq_bf + elems;
    unsigned short* xv_bf = xk_bf + elems;

    unsigned short* qbf   = (unsigned short*)d_ws;
    unsigned short* kbf   = qbf + elems;
    unsigned short* vbf   = kbf + elems;
    unsigned short* abf   = vbf + elems;
    unsigned short* wq_bf = abf + elems;
    unsigned short* wk_bf = wq_bf + welems;
    unsigned short* wv_bf = wk_bf + welems;
    unsigned short* wo_bf = wv_bf + welems;

    CvtArgs ca;
    ca.src[0] = query; ca.dst[0] = xq_bf; ca.n8[0] = (int)(elems / 8);
    ca.src[1] = key;   ca.dst[1] = xk_bf; ca.n8[1] = (int)(elems / 8);
    ca.src[2] = value; ca.dst[2] = xv_bf; ca.n8[2] = (int)(elems / 8);
    ca.src[3] = wq;    ca.dst[3] = wq_bf; ca.n8[3] = (int)(welems / 8);
    ca.src[4] = wk;    ca.dst[4] = wk_bf; ca.n8[4] = (int)(welems / 8);
    ca.src[5] = wv;    ca.dst[5] = wv_bf; ca.n8[5] = (int)(welems / 8);
    ca.src[6] = wo;    ca.dst[6] = wo_bf; ca.n8[6] = (int)(welems / 8);
    cvt_kernel<<<dim3(512, 7, 1), 256, 0, stream>>>(ca);

    gemm_kernel<0><<<dim3(ND / BN, (NB * NS) / BM, 3), 256, 0, stream>>>(
        xq_bf, xk_bf, xv_bf, wq_bf, wk_bf, wv_bf, bq, bk, bv, qbf, kbf, vbf);

    attn_kernel<<<dim3(NS / 64, NB * NH), 256, 0, stream>>>(
        qbf, kbf, vbf, amask, probs, abf);

    gemm_kernel<1><<<dim3(ND / BN, (NB * NS) / BM, 1), 256, 0, stream>>>(
        abf, abf, abf, wo_bf, wo_bf, wo_bf, bo, bo, bo, out, out, out);
}